// Round 10
// baseline (109.654 us; speedup 1.0000x reference)
//
#include <hip/hip_runtime.h>
#include <math.h>

#define NSAMP 4
#define NB 64
#define LVOL (64*64*64)
#define WPS 128                 // hist blocks per sample (512 total)
#define NFIN 64                 // finisher blocks per sample (last 64 arrivals)
#define TILEB (68*64)           // 4352 B per k-block (68 rows x 32 k x 2B bf16)
#define KBLK 4                  // 4 k-blocks x 32 voxels = 128 voxels per iter
#define AREG (KBLK*TILEB)       // 17408 B per matrix region
#define LDSB (2*AREG)           // 34816 B total
// XOR-swizzle byte-addr bits 4..6 by row bits 1..3; applied identically on
// scatter-write, rezero, and frag-read. Bijective within each tile; all
// region bases (kb*TILEB, AREG) are multiples of 128 -> commute with SWZ.
#define SWZ(a,row) ((a) ^ ((((row)>>1)&7)<<4))

typedef __attribute__((ext_vector_type(8))) short bf16x8;
typedef __attribute__((ext_vector_type(4))) float f32x4;

__device__ __forceinline__ unsigned short f2bf(float x){  // RNE f32->bf16
  unsigned u = __float_as_uint(x);
  return (unsigned short)((u + 0x7FFFu + ((u >> 16) & 1u)) >> 16);
}
// device-coherent (cross-XCD visible) relaxed float store/load; coalesced,
// non-RMW -> no contention serialization (the R9 lesson).
__device__ __forceinline__ void stc(float* p, float v){
  __hip_atomic_store(p, v, __ATOMIC_RELAXED, __HIP_MEMORY_SCOPE_AGENT);
}
__device__ __forceinline__ float ldc(const float* p){
  return __hip_atomic_load(p, __ATOMIC_RELAXED, __HIP_MEMORY_SCOPE_AGENT);
}

// ---- kernel 1: per-chunk min/max partials; zeroes the chain counters ----
__global__ __launch_bounds__(256) void k_minmax(const float* __restrict__ tgt,
                                                const float* __restrict__ src,
                                                float4* __restrict__ mmp,
                                                int* __restrict__ cnt){
  if (blockIdx.x == 0 && threadIdx.x < 16) cnt[threadIdx.x] = 0;
  const int n = blockIdx.x >> 7, chunk = blockIdx.x & 127;  // 128 chunks/sample
  const float4* t4 = (const float4*)(tgt + (size_t)n * LVOL) + (size_t)chunk * 256;
  const float4* s4 = (const float4*)(src + (size_t)n * LVOL) + (size_t)chunk * 256;
  float4 a = t4[threadIdx.x];
  float4 b = s4[threadIdx.x];
  float tmn = fminf(fminf(a.x, a.y), fminf(a.z, a.w));
  float tmx = fmaxf(fmaxf(a.x, a.y), fmaxf(a.z, a.w));
  float smn = fminf(fminf(b.x, b.y), fminf(b.z, b.w));
  float smx = fmaxf(fmaxf(b.x, b.y), fmaxf(b.z, b.w));
  for (int off = 32; off; off >>= 1){
    tmn = fminf(tmn, __shfl_down(tmn, off));
    tmx = fmaxf(tmx, __shfl_down(tmx, off));
    smn = fminf(smn, __shfl_down(smn, off));
    smx = fmaxf(smx, __shfl_down(smx, off));
  }
  __shared__ float red[4][4];
  const int wave = threadIdx.x >> 6, lane = threadIdx.x & 63;
  if (lane == 0){ red[wave][0]=tmn; red[wave][1]=tmx; red[wave][2]=smn; red[wave][3]=smx; }
  __syncthreads();
  if (threadIdx.x == 0){
    for (int w = 1; w < 4; ++w){
      tmn = fminf(tmn, red[w][0]); tmx = fmaxf(tmx, red[w][1]);
      smn = fminf(smn, red[w][2]); smx = fmaxf(smx, red[w][3]);
    }
    mmp[blockIdx.x] = make_float4(tmn, tmx, smn, smx);
  }
}

// ---- kernel 2: MFMA hist GEMM + in-kernel chained finish ----
// GEMM core identical to rounds 8/9 (verified). Epilogue: coherent P stores
// (no contention), chained counters: last NFIN arrivals per sample spin till
// all WPS partials stored, reduce 64-bin slices; last finisher does entropy;
// last sample writes out.
__global__ __launch_bounds__(256, 4) void k_hist(const float* __restrict__ tgt,
                                                 const float* __restrict__ src,
                                                 const float4* __restrict__ mmp,
                                                 float* __restrict__ P,
                                                 float* __restrict__ hist,
                                                 float* __restrict__ ratio,
                                                 int* __restrict__ cnt,
                                                 float* __restrict__ out){
  __shared__ __align__(16) char lds[LDSB];
  __shared__ int fl;
  __shared__ float shred[4][64];
  __shared__ float rowsum[NB], colsum[NB], wr1[4], wr2[4], S_sh;
  const int tid = threadIdx.x, wv = tid >> 6, lane = tid & 63;
  const int n = blockIdx.x >> 7, wg = blockIdx.x & (WPS - 1);

  // per-wave redundant minmax reduce over this sample's 128 partials
  float4 v = mmp[n * 128 + lane];
  float4 v2 = mmp[n * 128 + 64 + lane];
  v.x = fminf(v.x, v2.x); v.y = fmaxf(v.y, v2.y);
  v.z = fminf(v.z, v2.z); v.w = fmaxf(v.w, v2.w);
  for (int off = 32; off; off >>= 1){
    v.x = fminf(v.x, __shfl_down(v.x, off));
    v.y = fmaxf(v.y, __shfl_down(v.y, off));
    v.z = fminf(v.z, __shfl_down(v.z, off));
    v.w = fmaxf(v.w, __shfl_down(v.w, off));
  }
  const float tmn = __shfl(v.x, 0), tmx = __shfl(v.y, 0);
  const float smn = __shfl(v.z, 0), smx = __shfl(v.w, 0);
  const float st = (float)NB / (tmx - tmn + 1e-12f);
  const float ss = (float)NB / (smx - smn + 1e-12f);

  // zero the tiles (2176 int4)
  {
    int4 zz = make_int4(0, 0, 0, 0);
    #pragma unroll
    for (int i = 0; i < 9; ++i){
      int idx = tid + i * 256;
      if (idx < LDSB / 16) ((int4*)lds)[idx] = zz;
    }
  }

  // scatter role (uniform per wave): half=0 -> T into A region, half=1 -> S
  const int half = tid >> 7, v7 = tid & 127;
  const int kb_w = v7 >> 5, k2 = v7 & 31;
  const int sbase = half * AREG + kb_w * TILEB + k2 * 2;
  const float mn = half ? smn : tmn;
  const float sc = half ? ss : st;
  const float* gsrc = half ? src : tgt;
  const size_t gbase = (size_t)n * LVOL + (size_t)wg * 2048 + v7;

  // fragment read offsets: wave's 32x32 quadrant
  const int r = lane & 15, g = lane >> 4;
  const int rb = 32 * (wv >> 1), cb = 32 * (wv & 1);
  int sa[2], sb[2];
  #pragma unroll
  for (int i = 0; i < 2; ++i){
    int ar = 1 + rb + 16 * i + r;
    sa[i] = SWZ(ar * 64 + g * 16, ar);
    int br = 1 + cb + 16 * i + r;
    sb[i] = AREG + SWZ(br * 64 + g * 16, br);
  }
  f32x4 acc[2][2];
  #pragma unroll
  for (int ai = 0; ai < 2; ++ai)
    #pragma unroll
    for (int bj = 0; bj < 2; ++bj) acc[ai][bj] = (f32x4){0.f, 0.f, 0.f, 0.f};

  int piu = 0;
  for (int it = 0; it < 16; ++it){
    __syncthreads();                         // prev-iter reads (or zero-init) done
    if (it){                                 // rezero exactly the 4 slots we wrote
      #pragma unroll
      for (int a = 0; a < 4; ++a){
        int row = piu + a;
        *(unsigned short*)(lds + SWZ(sbase + row * 64, row)) = 0;
      }
    }
    const float val = gsrc[gbase + (size_t)it * 128];
    {
      float u = (val - mn) * sc;
      float fu = floorf(u); int iu = (int)fu; float f = u - fu, q = 1.f - f;
      float w0 = q*q*q*(1.f/6.f), w3 = f*f*f*(1.f/6.f);
      float w1 = (2.f/3.f) - f*f + 0.5f*f*f*f, w2 = 1.f - w0 - w1 - w3;
      float w[4] = {w0, w1, w2, w3};
      piu = iu;
      #pragma unroll
      for (int a = 0; a < 4; ++a){
        int row = iu + a;                    // lds row = bin+1
        *(unsigned short*)(lds + SWZ(sbase + row * 64, row)) = f2bf(w[a]);
      }
    }
    __syncthreads();                         // all columns scattered
    #pragma unroll
    for (int kb = 0; kb < KBLK; ++kb){
      const char* p = lds + kb * TILEB;
      bf16x8 a0 = *(const bf16x8*)(p + sa[0]);
      bf16x8 a1 = *(const bf16x8*)(p + sa[1]);
      bf16x8 b0 = *(const bf16x8*)(p + sb[0]);
      bf16x8 b1 = *(const bf16x8*)(p + sb[1]);
      acc[0][0] = __builtin_amdgcn_mfma_f32_16x16x32_bf16(a0, b0, acc[0][0], 0, 0, 0);
      acc[0][1] = __builtin_amdgcn_mfma_f32_16x16x32_bf16(a0, b1, acc[0][1], 0, 0, 0);
      acc[1][0] = __builtin_amdgcn_mfma_f32_16x16x32_bf16(a1, b0, acc[1][0], 0, 0, 0);
      acc[1][1] = __builtin_amdgcn_mfma_f32_16x16x32_bf16(a1, b1, acc[1][1], 0, 0, 0);
    }
  }
  // epilogue: coherent stores of wave's quadrant into this block's P slice.
  // C/D map col=lane&15 (r), row=(lane>>4)*4+e (m89-verified).
  {
    float* Pp = P + (size_t)blockIdx.x * 4096;
    #pragma unroll
    for (int ai = 0; ai < 2; ++ai)
      #pragma unroll
      for (int bj = 0; bj < 2; ++bj)
        #pragma unroll
        for (int e = 0; e < 4; ++e)
          stc(&Pp[(rb + 16 * ai + g * 4 + e) * 64 + cb + 16 * bj + r],
              acc[ai][bj][e]);
  }
  __threadfence();                           // drain own stores
  __syncthreads();                           // all threads' stores drained
  if (tid == 0) fl = atomicAdd(&cnt[n], 1);
  __syncthreads();
  const int f = fl;
  if (f < WPS - NFIN) return;                // not a finisher
  // spin until all WPS partials of sample n are stored
  if (tid == 0){
    while (__hip_atomic_load(&cnt[n], __ATOMIC_RELAXED, __HIP_MEMORY_SCOPE_AGENT) < WPS)
      __builtin_amdgcn_s_sleep(2);
  }
  __syncthreads();

  // ---- finisher: reduce 64-bin slice across 128 partials ----
  const int fid = f - (WPS - NFIN);          // 0..63
  const float* Pn = P + (size_t)n * WPS * 4096;
  {
    const int b6 = tid & 63, g4 = tid >> 6;  // bin-in-slice, partial-group
    const int bin = fid * 64 + b6;
    float s = 0.f;
    #pragma unroll 8
    for (int w = g4 * 32; w < g4 * 32 + 32; ++w)
      s += ldc(&Pn[(size_t)w * 4096 + bin]);
    shred[g4][b6] = s;
  }
  __syncthreads();
  if (tid < 64){
    float s = shred[0][tid] + shred[1][tid] + shred[2][tid] + shred[3][tid];
    stc(&hist[n * 4096 + fid * 64 + tid], s);
  }
  __threadfence();
  __syncthreads();
  if (tid == 0) fl = atomicAdd(&cnt[NSAMP + n], 1);
  __syncthreads();
  if (fl != NFIN - 1) return;                // not the last finisher
  __threadfence();

  // ---- entropy tail for sample n (one block) ----
  const float* h = hist + n * 4096;
  if (tid < NB){ rowsum[tid] = 0.f; colsum[tid] = 0.f; }
  __syncthreads();
  const int rr = tid >> 2, c0 = (tid & 3) * 16;
  float hv[16];
  float rsum = 0.f;
  #pragma unroll
  for (int k = 0; k < 16; ++k){
    hv[k] = ldc(&h[rr * 64 + c0 + k]);       // coherent read
    rsum += hv[k];
  }
  atomicAdd(&rowsum[rr], rsum);
  #pragma unroll
  for (int k = 0; k < 16; ++k) atomicAdd(&colsum[c0 + k], hv[k]);
  float part = rsum;
  for (int off = 32; off; off >>= 1) part += __shfl_down(part, off);
  if ((tid & 63) == 0) wr1[tid >> 6] = part;
  __syncthreads();
  if (tid == 0) S_sh = wr1[0] + wr1[1] + wr1[2] + wr1[3];
  __syncthreads();
  const float invS = 1.f / S_sh;
  float ej = 0.f;
  #pragma unroll
  for (int k = 0; k < 16; ++k){
    float p = hv[k] * invS;
    ej -= p * logf(p + 1e-12f);
  }
  for (int off = 32; off; off >>= 1) ej += __shfl_down(ej, off);
  if ((tid & 63) == 0) wr2[tid >> 6] = ej;
  float em = 0.f;
  if (tid < NB){
    float pt = rowsum[tid] * invS;
    float ps = colsum[tid] * invS;
    em = -pt * logf(pt + 1e-12f) - ps * logf(ps + 1e-12f);
    for (int off = 32; off; off >>= 1) em += __shfl_down(em, off);
  }
  __syncthreads();
  if (tid == 0){
    float EJ = wr2[0] + wr2[1] + wr2[2] + wr2[3];
    stc(&ratio[n], em / EJ);
    __threadfence();
    int f2 = atomicAdd(&cnt[8], 1);
    if (f2 == NSAMP - 1){                    // last sample finisher
      __threadfence();
      float s = 0.f;
      #pragma unroll
      for (int m = 0; m < NSAMP; ++m) s += ldc(&ratio[m]);
      out[0] = -0.25f * s;
    }
  }
}

extern "C" void kernel_launch(void* const* d_in, const int* in_sizes, int n_in,
                              void* d_out, int out_size, void* d_ws, size_t ws_size,
                              hipStream_t stream){
  const float* tgt = (const float*)d_in[0];
  const float* src = (const float*)d_in[1];
  float* out = (float*)d_out;
  char* ws = (char*)d_ws;
  // ws: [0,8K) mmp 512*float4 | [8K,+64) cnt | [8320,+16) ratio |
  //     [8448,+64K) hist | [73984, +8.4MB) P partials
  float4* mmp = (float4*)ws;
  int*   cnt  = (int*)(ws + 8192);
  float* ratio= (float*)(ws + 8320);
  float* hist = (float*)(ws + 8448);
  float* P    = (float*)(ws + 73984);
  k_minmax<<<NSAMP * 128, 256, 0, stream>>>(tgt, src, mmp, cnt);
  k_hist  <<<NSAMP * WPS, 256, 0, stream>>>(tgt, src, mmp, P, hist, ratio, cnt, out);
}

// Round 11
// 66.151 us; speedup vs baseline: 1.6576x; 1.6576x over previous
//
#include <hip/hip_runtime.h>
#include <math.h>

#define NSAMP 4
#define NB 64
#define LVOL (64*64*64)
#define TILEB (68*64)           // 4352 B per k-block (68 rows x 32 k x 2B bf16)
#define KBLK 4                  // 4 k-blocks x 32 voxels = 128 voxels per iter
#define AREG (KBLK*TILEB)       // 17408 B per matrix region
#define LDSB (2*AREG)           // 34816 B total -> 4 blocks/CU
// XOR-swizzle byte-addr bits 4..6 by row bits 1..3; applied identically on
// scatter-write, rezero, and frag-read. Bijective within each tile; all
// region bases (kb*TILEB, AREG) are multiples of 128 -> commute with SWZ.
#define SWZ(a,row) ((a) ^ ((((row)>>1)&7)<<4))

typedef __attribute__((ext_vector_type(8))) short bf16x8;
typedef __attribute__((ext_vector_type(4))) float f32x4;

__device__ __forceinline__ unsigned short f2bf(float x){  // RNE f32->bf16
  unsigned u = __float_as_uint(x);
  return (unsigned short)((u + 0x7FFFu + ((u >> 16) & 1u)) >> 16);
}

// ---- kernel 1: per-chunk min/max partials; zeroes the chain counters ----
__global__ __launch_bounds__(256) void k_minmax(const float* __restrict__ tgt,
                                                const float* __restrict__ src,
                                                float4* __restrict__ mmp,
                                                int* __restrict__ cnt){
  if (blockIdx.x == 0 && threadIdx.x < 8) cnt[threadIdx.x] = 0;
  const int n = blockIdx.x >> 6, chunk = blockIdx.x & 63;   // 64 chunks/sample
  const float4* t4 = (const float4*)(tgt + (size_t)n * LVOL) + (size_t)chunk * 1024;
  const float4* s4 = (const float4*)(src + (size_t)n * LVOL) + (size_t)chunk * 1024;
  float tmn = INFINITY, tmx = -INFINITY, smn = INFINITY, smx = -INFINITY;
  #pragma unroll
  for (int i = 0; i < 4; ++i){
    float4 a = t4[threadIdx.x + i * 256];
    tmn = fminf(tmn, fminf(fminf(a.x, a.y), fminf(a.z, a.w)));
    tmx = fmaxf(tmx, fmaxf(fmaxf(a.x, a.y), fmaxf(a.z, a.w)));
    float4 b = s4[threadIdx.x + i * 256];
    smn = fminf(smn, fminf(fminf(b.x, b.y), fminf(b.z, b.w)));
    smx = fmaxf(smx, fmaxf(fmaxf(b.x, b.y), fmaxf(b.z, b.w)));
  }
  for (int off = 32; off; off >>= 1){
    tmn = fminf(tmn, __shfl_down(tmn, off));
    tmx = fmaxf(tmx, __shfl_down(tmx, off));
    smn = fminf(smn, __shfl_down(smn, off));
    smx = fmaxf(smx, __shfl_down(smx, off));
  }
  __shared__ float red[4][4];
  const int wave = threadIdx.x >> 6, lane = threadIdx.x & 63;
  if (lane == 0){ red[wave][0]=tmn; red[wave][1]=tmx; red[wave][2]=smn; red[wave][3]=smx; }
  __syncthreads();
  if (threadIdx.x == 0){
    for (int w = 1; w < 4; ++w){
      tmn = fminf(tmn, red[w][0]); tmx = fmaxf(tmx, red[w][1]);
      smn = fminf(smn, red[w][2]); smx = fmaxf(smx, red[w][3]);
    }
    mmp[blockIdx.x] = make_float4(tmn, tmx, smn, smx);
  }
}

// ---- kernel 2: shared-tile bf16 MFMA hist GEMM (4 blocks/CU) ----
// R8-proven core. Per 128-voxel iter: tid<128 scatters T-weights, tid>=128
// scatters S-weights (each voxel owns its K-column -> non-atomic). Each wave
// computes a 32x32 output quadrant: 4 b128 reads + 4 MFMA per kb. Plain
// stores of the per-block partial to P (cross-kernel visibility).
__global__ __launch_bounds__(256, 4) void k_hist(const float* __restrict__ tgt,
                                                 const float* __restrict__ src,
                                                 const float4* __restrict__ mmp,
                                                 float* __restrict__ P,
                                                 int wpsl, int vper, int iters){
  __shared__ __align__(16) char lds[LDSB];
  const int tid = threadIdx.x, wv = tid >> 6, lane = tid & 63;
  const int n = blockIdx.x >> wpsl, wg = blockIdx.x & ((1 << wpsl) - 1);

  // per-wave redundant minmax reduce over this sample's 64 partials
  float4 v = mmp[n * 64 + lane];
  for (int off = 32; off; off >>= 1){
    v.x = fminf(v.x, __shfl_down(v.x, off));
    v.y = fmaxf(v.y, __shfl_down(v.y, off));
    v.z = fminf(v.z, __shfl_down(v.z, off));
    v.w = fmaxf(v.w, __shfl_down(v.w, off));
  }
  const float tmn = __shfl(v.x, 0), tmx = __shfl(v.y, 0);
  const float smn = __shfl(v.z, 0), smx = __shfl(v.w, 0);
  const float st = (float)NB / (tmx - tmn + 1e-12f);
  const float ss = (float)NB / (smx - smn + 1e-12f);

  // zero the tiles (2176 int4)
  {
    int4 zz = make_int4(0, 0, 0, 0);
    #pragma unroll
    for (int i = 0; i < 9; ++i){
      int idx = tid + i * 256;
      if (idx < LDSB / 16) ((int4*)lds)[idx] = zz;
    }
  }

  // scatter role (uniform per wave): half=0 -> T into A region, half=1 -> S
  const int half = tid >> 7, v7 = tid & 127;
  const int kb_w = v7 >> 5, k2 = v7 & 31;
  const int sbase = half * AREG + kb_w * TILEB + k2 * 2;
  const float mn = half ? smn : tmn;
  const float sc = half ? ss : st;
  const float* gsrc = half ? src : tgt;
  const size_t gbase = (size_t)n * LVOL + (size_t)wg * vper + v7;

  // fragment read offsets: wave's 32x32 quadrant
  const int r = lane & 15, g = lane >> 4;
  const int rb = 32 * (wv >> 1), cb = 32 * (wv & 1);
  int sa[2], sb[2];
  #pragma unroll
  for (int i = 0; i < 2; ++i){
    int ar = 1 + rb + 16 * i + r;
    sa[i] = SWZ(ar * 64 + g * 16, ar);
    int br = 1 + cb + 16 * i + r;
    sb[i] = AREG + SWZ(br * 64 + g * 16, br);
  }
  f32x4 acc[2][2];
  #pragma unroll
  for (int ai = 0; ai < 2; ++ai)
    #pragma unroll
    for (int bj = 0; bj < 2; ++bj) acc[ai][bj] = (f32x4){0.f, 0.f, 0.f, 0.f};

  int piu = 0;
  for (int it = 0; it < iters; ++it){
    __syncthreads();                         // prev-iter reads (or zero-init) done
    if (it){                                 // rezero exactly the 4 slots we wrote
      #pragma unroll
      for (int a = 0; a < 4; ++a){
        int row = piu + a;
        *(unsigned short*)(lds + SWZ(sbase + row * 64, row)) = 0;
      }
    }
    const float val = gsrc[gbase + (size_t)it * 128];
    {
      float u = (val - mn) * sc;
      float fu = floorf(u); int iu = (int)fu; float f = u - fu, q = 1.f - f;
      float w0 = q*q*q*(1.f/6.f), w3 = f*f*f*(1.f/6.f);
      float w1 = (2.f/3.f) - f*f + 0.5f*f*f*f, w2 = 1.f - w0 - w1 - w3;
      float w[4] = {w0, w1, w2, w3};
      piu = iu;
      #pragma unroll
      for (int a = 0; a < 4; ++a){
        int row = iu + a;                    // lds row = bin+1
        *(unsigned short*)(lds + SWZ(sbase + row * 64, row)) = f2bf(w[a]);
      }
    }
    __syncthreads();                         // all columns scattered
    #pragma unroll
    for (int kb = 0; kb < KBLK; ++kb){
      const char* p = lds + kb * TILEB;
      bf16x8 a0 = *(const bf16x8*)(p + sa[0]);
      bf16x8 a1 = *(const bf16x8*)(p + sa[1]);
      bf16x8 b0 = *(const bf16x8*)(p + sb[0]);
      bf16x8 b1 = *(const bf16x8*)(p + sb[1]);
      acc[0][0] = __builtin_amdgcn_mfma_f32_16x16x32_bf16(a0, b0, acc[0][0], 0, 0, 0);
      acc[0][1] = __builtin_amdgcn_mfma_f32_16x16x32_bf16(a0, b1, acc[0][1], 0, 0, 0);
      acc[1][0] = __builtin_amdgcn_mfma_f32_16x16x32_bf16(a1, b0, acc[1][0], 0, 0, 0);
      acc[1][1] = __builtin_amdgcn_mfma_f32_16x16x32_bf16(a1, b1, acc[1][1], 0, 0, 0);
    }
  }
  // epilogue: each wave owns a distinct 32x32 quadrant -> direct plain stores.
  // C/D map col=lane&15 (r), row=(lane>>4)*4+e (m89-verified).
  float* Pp = P + (size_t)blockIdx.x * 4096;
  #pragma unroll
  for (int ai = 0; ai < 2; ++ai)
    #pragma unroll
    for (int bj = 0; bj < 2; ++bj)
      #pragma unroll
      for (int e = 0; e < 4; ++e)
        Pp[(rb + 16 * ai + g * 4 + e) * 64 + cb + 16 * bj + r] = acc[ai][bj][e];
}

// ---- kernel 3: reduce partials -> hist -> entropies -> output, chained ----
// 256 blocks: block (n, c=0..63) reduces 16 float4 (64 bins) across wps
// partials, split over 16 thread-groups (wps/16 each) + LDS tree. Last
// finisher per sample computes entropies; last sample-finisher writes out.
// Cross-block reads in-kernel use atomicAdd(p, 0).
__global__ __launch_bounds__(256) void k_finish(const float* __restrict__ P,
                                                float* __restrict__ hist,
                                                float* __restrict__ ratio,
                                                int* __restrict__ cnt,
                                                float* __restrict__ out, int wps){
  __shared__ float4 sh4[16][17];
  __shared__ int flag;
  __shared__ float rowsum[NB], colsum[NB], wr1[4], wr2[4], S_sh;
  const int tid = threadIdx.x;
  const int n = blockIdx.x >> 6, c = blockIdx.x & 63;
  const int per = wps >> 4;
  // phase A: hist[n][c*64 .. c*64+64) = sum over wps partials
  {
    const int fi = tid & 15, p4 = tid >> 4;           // 16 float4 x 16 groups
    const float4* P4 = (const float4*)P;
    size_t base = ((size_t)n * wps + (size_t)p4 * per) * 1024 + c * 16 + fi;
    float4 acc = make_float4(0.f, 0.f, 0.f, 0.f);
    for (int w = 0; w < per; ++w){
      float4 vv = P4[base + (size_t)w * 1024];
      acc.x += vv.x; acc.y += vv.y; acc.z += vv.z; acc.w += vv.w;
    }
    sh4[p4][fi] = acc;
    __syncthreads();
    if (tid < 16){
      float4 s = sh4[0][tid];
      #pragma unroll
      for (int p = 1; p < 16; ++p){
        float4 a = sh4[p][tid];
        s.x += a.x; s.y += a.y; s.z += a.z; s.w += a.w;
      }
      ((float4*)hist)[(size_t)n * 1024 + c * 16 + tid] = s;
    }
  }
  __threadfence();
  __syncthreads();
  if (tid == 0) flag = atomicAdd(&cnt[n], 1);
  __syncthreads();
  if (flag != 63) return;                           // not the last chunk
  __threadfence();
  // phase B: entropies for sample n (this block only)
  float* h = hist + n * 4096;
  if (tid < NB){ rowsum[tid] = 0.f; colsum[tid] = 0.f; }
  __syncthreads();
  const int rr = tid >> 2, c0 = (tid & 3) * 16;
  float hv[16];
  float rsum = 0.f;
  #pragma unroll
  for (int k = 0; k < 16; ++k){
    hv[k] = atomicAdd(&h[rr * 64 + c0 + k], 0.f);   // coherent read
    rsum += hv[k];
  }
  atomicAdd(&rowsum[rr], rsum);
  #pragma unroll
  for (int k = 0; k < 16; ++k) atomicAdd(&colsum[c0 + k], hv[k]);
  float part = rsum;
  for (int off = 32; off; off >>= 1) part += __shfl_down(part, off);
  if ((tid & 63) == 0) wr1[tid >> 6] = part;
  __syncthreads();
  if (tid == 0) S_sh = wr1[0] + wr1[1] + wr1[2] + wr1[3];
  __syncthreads();
  const float invS = 1.f / S_sh;
  float ej = 0.f;
  #pragma unroll
  for (int k = 0; k < 16; ++k){
    float p = hv[k] * invS;
    ej -= p * logf(p + 1e-12f);
  }
  for (int off = 32; off; off >>= 1) ej += __shfl_down(ej, off);
  if ((tid & 63) == 0) wr2[tid >> 6] = ej;
  float em = 0.f;
  if (tid < NB){
    float pt = rowsum[tid] * invS;
    float ps = colsum[tid] * invS;
    em = -pt * logf(pt + 1e-12f) - ps * logf(ps + 1e-12f);
    for (int off = 32; off; off >>= 1) em += __shfl_down(em, off);
  }
  __syncthreads();
  if (tid == 0){
    float EJ = wr2[0] + wr2[1] + wr2[2] + wr2[3];
    ratio[n] = em / EJ;                             // (Ht + Hs) / Hj
    __threadfence();
    int f2 = atomicAdd(&cnt[4], 1);
    if (f2 == NSAMP - 1){                           // last sample finisher
      __threadfence();
      float s = 0.f;
      #pragma unroll
      for (int m = 0; m < NSAMP; ++m) s += atomicAdd(&ratio[m], 0.f);
      out[0] = -0.25f * s;
    }
  }
}

extern "C" void kernel_launch(void* const* d_in, const int* in_sizes, int n_in,
                              void* d_out, int out_size, void* d_ws, size_t ws_size,
                              hipStream_t stream){
  const float* tgt = (const float*)d_in[0];
  const float* src = (const float*)d_in[1];
  float* out = (float*)d_out;
  char* ws = (char*)d_ws;
  // ws: [0,4K) mmp 256*float4 | [4K,+32) cnt | [4352,+16) ratio |
  //     [4608,+64K) hist | [73728, ...) P partials
  float4* mmp = (float4*)ws;
  int*   cnt  = (int*)(ws + 4096);
  float* ratio= (float*)(ws + 4352);
  float* hist = (float*)(ws + 4608);
  float* P    = (float*)(ws + 73728);
  const size_t need256 = 73728ull + (size_t)NSAMP * 256 * 4096 * 4;  // ~16.8 MB
  const int wps  = (ws_size >= need256) ? 256 : 128;  // 1024 blocks = 4/CU
  const int wpsl = (wps == 256) ? 8 : 7;
  const int vper = LVOL / wps;
  const int iters = vper / 128;
  k_minmax<<<NSAMP * 64, 256, 0, stream>>>(tgt, src, mmp, cnt);
  k_hist  <<<NSAMP * wps, 256, 0, stream>>>(tgt, src, mmp, P, wpsl, vper, iters);
  k_finish<<<NSAMP * 64, 256, 0, stream>>>(P, hist, ratio, cnt, out, wps);
}

// Round 12
// 59.057 us; speedup vs baseline: 1.8568x; 1.1201x over previous
//
#include <hip/hip_runtime.h>
#include <math.h>

#define NSAMP 4
#define NB 64
#define LVOL (64*64*64)
#define WPS 128                 // hist blocks per sample (512 total)
#define TILEB (68*64)           // 4352 B per k-block (68 rows x 32 k x 2B bf16)
#define KBLK 4                  // 4 k-blocks x 32 voxels = 128 voxels per iter
#define AREG (KBLK*TILEB)       // 17408 B per matrix region
#define LDSB (2*AREG)           // 34816 B total
#define ZSTRIDE 68              // f32 reduce-zone col stride (16B-aligned rows)
// XOR-swizzle byte-addr bits 4..6 by row bits 1..3; applied identically on
// scatter-write, rezero, and frag-read. Bijective within each tile; all
// region bases (kb*TILEB, AREG) have bits 0-7 clear -> commute with SWZ.
#define SWZ(a,row) ((a) ^ ((((row)>>1)&7)<<4))

typedef __attribute__((ext_vector_type(8))) short bf16x8;
typedef __attribute__((ext_vector_type(4))) float f32x4;

__device__ __forceinline__ unsigned short f2bf(float x){  // RNE f32->bf16
  unsigned u = __float_as_uint(x);
  return (unsigned short)((u + 0x7FFFu + ((u >> 16) & 1u)) >> 16);
}

// ---- kernel 1: per-chunk min/max partials; zeroes the chain counters ----
__global__ __launch_bounds__(256) void k_minmax(const float* __restrict__ tgt,
                                                const float* __restrict__ src,
                                                float4* __restrict__ mmp,
                                                int* __restrict__ cnt){
  if (blockIdx.x == 0 && threadIdx.x < 8) cnt[threadIdx.x] = 0;
  const int n = blockIdx.x >> 6, chunk = blockIdx.x & 63;   // 64 chunks/sample
  const float4* t4 = (const float4*)(tgt + (size_t)n * LVOL) + (size_t)chunk * 1024;
  const float4* s4 = (const float4*)(src + (size_t)n * LVOL) + (size_t)chunk * 1024;
  float tmn = INFINITY, tmx = -INFINITY, smn = INFINITY, smx = -INFINITY;
  #pragma unroll
  for (int i = 0; i < 4; ++i){
    float4 a = t4[threadIdx.x + i * 256];
    tmn = fminf(tmn, fminf(fminf(a.x, a.y), fminf(a.z, a.w)));
    tmx = fmaxf(tmx, fmaxf(fmaxf(a.x, a.y), fmaxf(a.z, a.w)));
    float4 b = s4[threadIdx.x + i * 256];
    smn = fminf(smn, fminf(fminf(b.x, b.y), fminf(b.z, b.w)));
    smx = fmaxf(smx, fmaxf(fmaxf(b.x, b.y), fmaxf(b.z, b.w)));
  }
  for (int off = 32; off; off >>= 1){
    tmn = fminf(tmn, __shfl_down(tmn, off));
    tmx = fmaxf(tmx, __shfl_down(tmx, off));
    smn = fminf(smn, __shfl_down(smn, off));
    smx = fmaxf(smx, __shfl_down(smx, off));
  }
  __shared__ float red[4][4];
  const int wave = threadIdx.x >> 6, lane = threadIdx.x & 63;
  if (lane == 0){ red[wave][0]=tmn; red[wave][1]=tmx; red[wave][2]=smn; red[wave][3]=smx; }
  __syncthreads();
  if (threadIdx.x == 0){
    for (int w = 1; w < 4; ++w){
      tmn = fminf(tmn, red[w][0]); tmx = fmaxf(tmx, red[w][1]);
      smn = fminf(smn, red[w][2]); smx = fmaxf(smx, red[w][3]);
    }
    mmp[blockIdx.x] = make_float4(tmn, tmx, smn, smx);
  }
}

// ---- kernel 2: k-slice-per-wave bf16 MFMA hist GEMM ----
// Shared-tile scatter (proven): per 128-voxel iter, tid<128 scatters T,
// tid>=128 scatters S (voxel owns its K-column -> non-atomic). COMPUTE is
// k-sliced: wave w owns k-block w and computes the FULL 64x64 for its
// K-slice: 8 b128 reads (no duplication) + 16 MFMA per iter. Epilogue
// tree-reduces the 4 wave accs via two [64][68] f32 LDS zones.
__global__ __launch_bounds__(256, 2) void k_hist(const float* __restrict__ tgt,
                                                 const float* __restrict__ src,
                                                 const float4* __restrict__ mmp,
                                                 float* __restrict__ P){
  __shared__ __align__(16) char lds[LDSB];
  const int tid = threadIdx.x, wv = tid >> 6, lane = tid & 63;
  const int n = blockIdx.x >> 7, wg = blockIdx.x & (WPS - 1);

  // per-wave redundant minmax reduce over this sample's 64 partials
  float4 v = mmp[n * 64 + lane];
  for (int off = 32; off; off >>= 1){
    v.x = fminf(v.x, __shfl_down(v.x, off));
    v.y = fmaxf(v.y, __shfl_down(v.y, off));
    v.z = fminf(v.z, __shfl_down(v.z, off));
    v.w = fmaxf(v.w, __shfl_down(v.w, off));
  }
  const float tmn = __shfl(v.x, 0), tmx = __shfl(v.y, 0);
  const float smn = __shfl(v.z, 0), smx = __shfl(v.w, 0);
  const float st = (float)NB / (tmx - tmn + 1e-12f);
  const float ss = (float)NB / (smx - smn + 1e-12f);

  // zero the tiles (2176 int4)
  {
    int4 zz = make_int4(0, 0, 0, 0);
    #pragma unroll
    for (int i = 0; i < 9; ++i){
      int idx = tid + i * 256;
      if (idx < LDSB / 16) ((int4*)lds)[idx] = zz;
    }
  }

  // scatter role (uniform per wave): half=0 -> T into A region, half=1 -> S
  const int half = tid >> 7, v7 = tid & 127;
  const int kb_w = v7 >> 5, k2 = v7 & 31;
  const int sbase = half * AREG + kb_w * TILEB + k2 * 2;
  const float mn = half ? smn : tmn;
  const float sc = half ? ss : st;
  const float* gsrc = half ? src : tgt;
  const size_t gbase = (size_t)n * LVOL + (size_t)wg * 2048 + v7;

  // fragment read offsets: wave wv owns k-block wv; full 64x64 output
  const int r = lane & 15, g = lane >> 4;
  const char* pk = lds + wv * TILEB;           // this wave's k-block (A)
  int sa[4], sb[4];
  #pragma unroll
  for (int i = 0; i < 4; ++i){
    int row = 1 + 16 * i + r;
    sa[i] = SWZ(row * 64 + g * 16, row);
    sb[i] = AREG + sa[i];
  }
  f32x4 acc[4][4];
  #pragma unroll
  for (int ai = 0; ai < 4; ++ai)
    #pragma unroll
    for (int bj = 0; bj < 4; ++bj) acc[ai][bj] = (f32x4){0.f, 0.f, 0.f, 0.f};

  int piu = 0;
  for (int it = 0; it < 16; ++it){
    __syncthreads();                         // prev-iter reads (or zero-init) done
    if (it){                                 // rezero exactly the 4 slots we wrote
      #pragma unroll
      for (int a = 0; a < 4; ++a){
        int row = piu + a;
        *(unsigned short*)(lds + SWZ(sbase + row * 64, row)) = 0;
      }
    }
    const float val = gsrc[gbase + (size_t)it * 128];
    {
      float u = (val - mn) * sc;
      float fu = floorf(u); int iu = (int)fu; float f = u - fu, q = 1.f - f;
      float w0 = q*q*q*(1.f/6.f), w3 = f*f*f*(1.f/6.f);
      float w1 = (2.f/3.f) - f*f + 0.5f*f*f*f, w2 = 1.f - w0 - w1 - w3;
      float w[4] = {w0, w1, w2, w3};
      piu = iu;
      #pragma unroll
      for (int a = 0; a < 4; ++a){
        int row = iu + a;                    // lds row = bin+1
        *(unsigned short*)(lds + SWZ(sbase + row * 64, row)) = f2bf(w[a]);
      }
    }
    __syncthreads();                         // all columns scattered
    bf16x8 af[4], bfr[4];
    #pragma unroll
    for (int i = 0; i < 4; ++i) af[i]  = *(const bf16x8*)(pk + sa[i]);
    #pragma unroll
    for (int i = 0; i < 4; ++i) bfr[i] = *(const bf16x8*)(pk + sb[i]);
    #pragma unroll
    for (int ai = 0; ai < 4; ++ai)
      #pragma unroll
      for (int bj = 0; bj < 4; ++bj)
        acc[ai][bj] = __builtin_amdgcn_mfma_f32_16x16x32_bf16(af[ai], bfr[bj], acc[ai][bj], 0, 0, 0);
  }

  // ---- epilogue: tree-reduce 4 wave accs via two [64][68] f32 zones ----
  // C/D map col=lane&15 (r), row=(lane>>4)*4+e (m89-verified).
  float* z0 = (float*)lds;
  float* z1 = (float*)(lds + AREG);          // AREG = 64*68*4 exactly
  __syncthreads();                           // all frag reads done; reuse LDS
  if (wv >= 2){                              // waves 2,3 stage
    float* zf = (wv == 2) ? z0 : z1;
    #pragma unroll
    for (int ai = 0; ai < 4; ++ai)
      #pragma unroll
      for (int bj = 0; bj < 4; ++bj)
        #pragma unroll
        for (int e = 0; e < 4; ++e)
          zf[(16 * ai + g * 4 + e) * ZSTRIDE + 16 * bj + r] = acc[ai][bj][e];
  }
  __syncthreads();
  if (wv < 2){                               // waves 0,1 absorb
    const float* zf = (wv == 0) ? z0 : z1;
    #pragma unroll
    for (int ai = 0; ai < 4; ++ai)
      #pragma unroll
      for (int bj = 0; bj < 4; ++bj)
        #pragma unroll
        for (int e = 0; e < 4; ++e)
          acc[ai][bj][e] += zf[(16 * ai + g * 4 + e) * ZSTRIDE + 16 * bj + r];
  }
  __syncthreads();
  if (wv == 1){                              // wave 1 stages its partial sum
    #pragma unroll
    for (int ai = 0; ai < 4; ++ai)
      #pragma unroll
      for (int bj = 0; bj < 4; ++bj)
        #pragma unroll
        for (int e = 0; e < 4; ++e)
          z0[(16 * ai + g * 4 + e) * ZSTRIDE + 16 * bj + r] = acc[ai][bj][e];
  }
  __syncthreads();
  if (wv == 0){                              // wave 0: final sum + store to P
    #pragma unroll
    for (int ai = 0; ai < 4; ++ai)
      #pragma unroll
      for (int bj = 0; bj < 4; ++bj)
        #pragma unroll
        for (int e = 0; e < 4; ++e)
          acc[ai][bj][e] += z0[(16 * ai + g * 4 + e) * ZSTRIDE + 16 * bj + r];
    // stage final into z1 (b128-aligned rows), then vector-store to P
    #pragma unroll
    for (int ai = 0; ai < 4; ++ai)
      #pragma unroll
      for (int bj = 0; bj < 4; ++bj)
        #pragma unroll
        for (int e = 0; e < 4; ++e)
          z1[(16 * ai + g * 4 + e) * ZSTRIDE + 16 * bj + r] = acc[ai][bj][e];
    float4* Pp = (float4*)(P + (size_t)blockIdx.x * 4096);
    #pragma unroll
    for (int j = 0; j < 16; ++j){
      int i4 = j * 64 + lane;                // 0..1023 float4 slots
      int row = i4 >> 4, c4 = (i4 & 15) << 2;
      Pp[i4] = *(const float4*)&z1[row * ZSTRIDE + c4];
    }
  }
}

// ---- kernel 3: reduce partials -> hist -> entropies -> output, chained ----
// 256 blocks: block (n, c=0..63) reduces 16 float4 (64 bins) across 128
// partials, split over 16 thread-groups (8 each) + LDS tree. Last finisher
// per sample computes entropies; last sample-finisher writes out.
__global__ __launch_bounds__(256) void k_finish(const float* __restrict__ P,
                                                float* __restrict__ hist,
                                                float* __restrict__ ratio,
                                                int* __restrict__ cnt,
                                                float* __restrict__ out){
  __shared__ float4 sh4[16][17];
  __shared__ int flag;
  __shared__ float rowsum[NB], colsum[NB], wr1[4], wr2[4], S_sh;
  const int tid = threadIdx.x;
  const int n = blockIdx.x >> 6, c = blockIdx.x & 63;
  {
    const int fi = tid & 15, p4 = tid >> 4;           // 16 float4 x 16 groups
    const float4* P4 = (const float4*)P;
    size_t base = ((size_t)n * WPS + (size_t)p4 * 8) * 1024 + c * 16 + fi;
    float4 acc = make_float4(0.f, 0.f, 0.f, 0.f);
    #pragma unroll
    for (int w = 0; w < 8; ++w){
      float4 vv = P4[base + (size_t)w * 1024];
      acc.x += vv.x; acc.y += vv.y; acc.z += vv.z; acc.w += vv.w;
    }
    sh4[p4][fi] = acc;
    __syncthreads();
    if (tid < 16){
      float4 s = sh4[0][tid];
      #pragma unroll
      for (int p = 1; p < 16; ++p){
        float4 a = sh4[p][tid];
        s.x += a.x; s.y += a.y; s.z += a.z; s.w += a.w;
      }
      ((float4*)hist)[(size_t)n * 1024 + c * 16 + tid] = s;
    }
  }
  __threadfence();
  __syncthreads();
  if (tid == 0) flag = atomicAdd(&cnt[n], 1);
  __syncthreads();
  if (flag != 63) return;                           // not the last chunk
  __threadfence();
  // entropies for sample n (this block only)
  float* h = hist + n * 4096;
  if (tid < NB){ rowsum[tid] = 0.f; colsum[tid] = 0.f; }
  __syncthreads();
  const int rr = tid >> 2, c0 = (tid & 3) * 16;
  float hv[16];
  float rsum = 0.f;
  #pragma unroll
  for (int k = 0; k < 16; ++k){
    hv[k] = atomicAdd(&h[rr * 64 + c0 + k], 0.f);   // coherent read
    rsum += hv[k];
  }
  atomicAdd(&rowsum[rr], rsum);
  #pragma unroll
  for (int k = 0; k < 16; ++k) atomicAdd(&colsum[c0 + k], hv[k]);
  float part = rsum;
  for (int off = 32; off; off >>= 1) part += __shfl_down(part, off);
  if ((tid & 63) == 0) wr1[tid >> 6] = part;
  __syncthreads();
  if (tid == 0) S_sh = wr1[0] + wr1[1] + wr1[2] + wr1[3];
  __syncthreads();
  const float invS = 1.f / S_sh;
  float ej = 0.f;
  #pragma unroll
  for (int k = 0; k < 16; ++k){
    float p = hv[k] * invS;
    ej -= p * logf(p + 1e-12f);
  }
  for (int off = 32; off; off >>= 1) ej += __shfl_down(ej, off);
  if ((tid & 63) == 0) wr2[tid >> 6] = ej;
  float em = 0.f;
  if (tid < NB){
    float pt = rowsum[tid] * invS;
    float ps = colsum[tid] * invS;
    em = -pt * logf(pt + 1e-12f) - ps * logf(ps + 1e-12f);
    for (int off = 32; off; off >>= 1) em += __shfl_down(em, off);
  }
  __syncthreads();
  if (tid == 0){
    float EJ = wr2[0] + wr2[1] + wr2[2] + wr2[3];
    ratio[n] = em / EJ;                             // (Ht + Hs) / Hj
    __threadfence();
    int f2 = atomicAdd(&cnt[4], 1);
    if (f2 == NSAMP - 1){                           // last sample finisher
      __threadfence();
      float s = 0.f;
      #pragma unroll
      for (int m = 0; m < NSAMP; ++m) s += atomicAdd(&ratio[m], 0.f);
      out[0] = -0.25f * s;
    }
  }
}

extern "C" void kernel_launch(void* const* d_in, const int* in_sizes, int n_in,
                              void* d_out, int out_size, void* d_ws, size_t ws_size,
                              hipStream_t stream){
  const float* tgt = (const float*)d_in[0];
  const float* src = (const float*)d_in[1];
  float* out = (float*)d_out;
  char* ws = (char*)d_ws;
  // ws: [0,4K) mmp 256*float4 | [4K,+32) cnt | [4352,+16) ratio |
  //     [4608,+64K) hist | [73728, +8.4MB) P partials
  float4* mmp = (float4*)ws;
  int*   cnt  = (int*)(ws + 4096);
  float* ratio= (float*)(ws + 4352);
  float* hist = (float*)(ws + 4608);
  float* P    = (float*)(ws + 73728);
  k_minmax<<<NSAMP * 64, 256, 0, stream>>>(tgt, src, mmp, cnt);
  k_hist  <<<NSAMP * WPS, 256, 0, stream>>>(tgt, src, mmp, P);
  k_finish<<<NSAMP * 64, 256, 0, stream>>>(P, hist, ratio, cnt, out);
}

// Round 13
// 57.861 us; speedup vs baseline: 1.8951x; 1.0207x over previous
//
#include <hip/hip_runtime.h>
#include <math.h>

#define NSAMP 4
#define NB 64
#define LVOL (64*64*64)
#define WPS 128                 // hist blocks per sample (512 total)
#define TILEB (68*64)           // 4352 B per k-block (68 rows x 32 k x 2B bf16)
#define KBLK 4                  // 4 k-blocks x 32 voxels = 128 voxels per iter
#define AREG (KBLK*TILEB)       // 17408 B per matrix region
#define LDSB (2*AREG)           // 34816 B total -> 4 blocks/CU
#define ZSTRIDE 68              // f32 reduce-zone col stride (16B-aligned rows)
// XOR-swizzle byte-addr bits 4..6 by row bits 1..3; applied identically on
// scatter-write, rezero, and frag-read. Bijective within each tile; all
// region bases (kb*TILEB, AREG) have bits 0-7 clear -> commute with SWZ.
#define SWZ(a,row) ((a) ^ ((((row)>>1)&7)<<4))

typedef __attribute__((ext_vector_type(8))) short bf16x8;
typedef __attribute__((ext_vector_type(4))) float f32x4;

__device__ __forceinline__ unsigned short f2bf(float x){  // RNE f32->bf16
  unsigned u = __float_as_uint(x);
  return (unsigned short)((u + 0x7FFFu + ((u >> 16) & 1u)) >> 16);
}

// ---- kernel 1: per-chunk min/max partials; zeroes the chain counters ----
__global__ __launch_bounds__(256) void k_minmax(const float* __restrict__ tgt,
                                                const float* __restrict__ src,
                                                float4* __restrict__ mmp,
                                                int* __restrict__ cnt){
  if (blockIdx.x == 0 && threadIdx.x < 8) cnt[threadIdx.x] = 0;
  const int n = blockIdx.x >> 6, chunk = blockIdx.x & 63;   // 64 chunks/sample
  const float4* t4 = (const float4*)(tgt + (size_t)n * LVOL) + (size_t)chunk * 1024;
  const float4* s4 = (const float4*)(src + (size_t)n * LVOL) + (size_t)chunk * 1024;
  float tmn = INFINITY, tmx = -INFINITY, smn = INFINITY, smx = -INFINITY;
  #pragma unroll
  for (int i = 0; i < 4; ++i){
    float4 a = t4[threadIdx.x + i * 256];
    tmn = fminf(tmn, fminf(fminf(a.x, a.y), fminf(a.z, a.w)));
    tmx = fmaxf(tmx, fmaxf(fmaxf(a.x, a.y), fmaxf(a.z, a.w)));
    float4 b = s4[threadIdx.x + i * 256];
    smn = fminf(smn, fminf(fminf(b.x, b.y), fminf(b.z, b.w)));
    smx = fmaxf(smx, fmaxf(fmaxf(b.x, b.y), fmaxf(b.z, b.w)));
  }
  for (int off = 32; off; off >>= 1){
    tmn = fminf(tmn, __shfl_down(tmn, off));
    tmx = fmaxf(tmx, __shfl_down(tmx, off));
    smn = fminf(smn, __shfl_down(smn, off));
    smx = fmaxf(smx, __shfl_down(smx, off));
  }
  __shared__ float red[4][4];
  const int wave = threadIdx.x >> 6, lane = threadIdx.x & 63;
  if (lane == 0){ red[wave][0]=tmn; red[wave][1]=tmx; red[wave][2]=smn; red[wave][3]=smx; }
  __syncthreads();
  if (threadIdx.x == 0){
    for (int w = 1; w < 4; ++w){
      tmn = fminf(tmn, red[w][0]); tmx = fmaxf(tmx, red[w][1]);
      smn = fminf(smn, red[w][2]); smx = fmaxf(smx, red[w][3]);
    }
    mmp[blockIdx.x] = make_float4(tmn, tmx, smn, smx);
  }
}

// ---- kernel 2: k-slice-per-wave bf16 MFMA hist GEMM, register-preloaded ----
// The joint-hist GEMM is permutation-invariant in K: any voxel may occupy any
// k-column as long as T and S of the SAME voxel share the column (T-thread v7
// and S-thread v7+128 use identical voxel indices and the same fixed k-slot).
// So each thread preloads its 16 voxels as 4 coalesced float4s; the 16-iter
// loop is pure LDS/VALU/MFMA with zero global-memory latency inside.
__global__ __launch_bounds__(256, 2) void k_hist(const float* __restrict__ tgt,
                                                 const float* __restrict__ src,
                                                 const float4* __restrict__ mmp,
                                                 float* __restrict__ P){
  __shared__ __align__(16) char lds[LDSB];
  const int tid = threadIdx.x, wv = tid >> 6, lane = tid & 63;
  const int n = blockIdx.x >> 7, wg = blockIdx.x & (WPS - 1);

  // per-wave redundant minmax reduce over this sample's 64 partials
  float4 v = mmp[n * 64 + lane];
  for (int off = 32; off; off >>= 1){
    v.x = fminf(v.x, __shfl_down(v.x, off));
    v.y = fmaxf(v.y, __shfl_down(v.y, off));
    v.z = fminf(v.z, __shfl_down(v.z, off));
    v.w = fmaxf(v.w, __shfl_down(v.w, off));
  }
  const float tmn = __shfl(v.x, 0), tmx = __shfl(v.y, 0);
  const float smn = __shfl(v.z, 0), smx = __shfl(v.w, 0);
  const float st = (float)NB / (tmx - tmn + 1e-12f);
  const float ss = (float)NB / (smx - smn + 1e-12f);

  // scatter role (uniform per wave): half=0 -> T into A region, half=1 -> S
  const int half = tid >> 7, v7 = tid & 127;
  const int kb_w = v7 >> 5, k2 = v7 & 31;
  const int sbase = half * AREG + kb_w * TILEB + k2 * 2;
  const float mn = half ? smn : tmn;
  const float sc = half ? ss : st;
  const float* gsrc = half ? src : tgt;
  // preload 16 voxels = 4 coalesced float4s (consecutive v7 -> consecutive f4)
  const float4* g4 = (const float4*)(gsrc + (size_t)n * LVOL) + (size_t)wg * 512;
  float4 pre[4];
  #pragma unroll
  for (int g_ = 0; g_ < 4; ++g_) pre[g_] = g4[g_ * 128 + v7];

  // zero the tiles (2176 int4)
  {
    int4 zz = make_int4(0, 0, 0, 0);
    #pragma unroll
    for (int i = 0; i < 9; ++i){
      int idx = tid + i * 256;
      if (idx < LDSB / 16) ((int4*)lds)[idx] = zz;
    }
  }

  // fragment read offsets: wave wv owns k-block wv; full 64x64 output
  const int r = lane & 15, g = lane >> 4;
  const char* pk = lds + wv * TILEB;           // this wave's k-block (A)
  int sa[4], sb[4];
  #pragma unroll
  for (int i = 0; i < 4; ++i){
    int row = 1 + 16 * i + r;
    sa[i] = SWZ(row * 64 + g * 16, row);
    sb[i] = AREG + sa[i];
  }
  f32x4 acc[4][4];
  #pragma unroll
  for (int ai = 0; ai < 4; ++ai)
    #pragma unroll
    for (int bj = 0; bj < 4; ++bj) acc[ai][bj] = (f32x4){0.f, 0.f, 0.f, 0.f};

  int piu = 0;
  #pragma unroll
  for (int it = 0; it < 16; ++it){
    __syncthreads();                         // prev-iter reads (or zero-init) done
    if (it){                                 // rezero exactly the 4 slots we wrote
      #pragma unroll
      for (int a = 0; a < 4; ++a){
        int row = piu + a;
        *(unsigned short*)(lds + SWZ(sbase + row * 64, row)) = 0;
      }
    }
    // voxel for this iter from registers (static index: loop fully unrolled)
    const float4 pg = pre[it >> 2];
    const float val = (it & 3) == 0 ? pg.x : (it & 3) == 1 ? pg.y
                    : (it & 3) == 2 ? pg.z : pg.w;
    {
      float u = (val - mn) * sc;
      float fu = floorf(u); int iu = (int)fu; float f = u - fu, q = 1.f - f;
      float w0 = q*q*q*(1.f/6.f), w3 = f*f*f*(1.f/6.f);
      float w1 = (2.f/3.f) - f*f + 0.5f*f*f*f, w2 = 1.f - w0 - w1 - w3;
      float w[4] = {w0, w1, w2, w3};
      piu = iu;
      #pragma unroll
      for (int a = 0; a < 4; ++a){
        int row = iu + a;                    // lds row = bin+1
        *(unsigned short*)(lds + SWZ(sbase + row * 64, row)) = f2bf(w[a]);
      }
    }
    __syncthreads();                         // all columns scattered
    bf16x8 af[4], bfr[4];
    #pragma unroll
    for (int i = 0; i < 4; ++i) af[i]  = *(const bf16x8*)(pk + sa[i]);
    #pragma unroll
    for (int i = 0; i < 4; ++i) bfr[i] = *(const bf16x8*)(pk + sb[i]);
    #pragma unroll
    for (int ai = 0; ai < 4; ++ai)
      #pragma unroll
      for (int bj = 0; bj < 4; ++bj)
        acc[ai][bj] = __builtin_amdgcn_mfma_f32_16x16x32_bf16(af[ai], bfr[bj], acc[ai][bj], 0, 0, 0);
  }

  // ---- epilogue: tree-reduce 4 wave accs via two [64][68] f32 zones ----
  // C/D map col=lane&15 (r), row=(lane>>4)*4+e (m89-verified).
  float* z0 = (float*)lds;
  float* z1 = (float*)(lds + AREG);          // AREG = 64*68*4 exactly
  __syncthreads();                           // all frag reads done; reuse LDS
  if (wv >= 2){                              // waves 2,3 stage
    float* zf = (wv == 2) ? z0 : z1;
    #pragma unroll
    for (int ai = 0; ai < 4; ++ai)
      #pragma unroll
      for (int bj = 0; bj < 4; ++bj)
        #pragma unroll
        for (int e = 0; e < 4; ++e)
          zf[(16 * ai + g * 4 + e) * ZSTRIDE + 16 * bj + r] = acc[ai][bj][e];
  }
  __syncthreads();
  if (wv < 2){                               // waves 0,1 absorb
    const float* zf = (wv == 0) ? z0 : z1;
    #pragma unroll
    for (int ai = 0; ai < 4; ++ai)
      #pragma unroll
      for (int bj = 0; bj < 4; ++bj)
        #pragma unroll
        for (int e = 0; e < 4; ++e)
          acc[ai][bj][e] += zf[(16 * ai + g * 4 + e) * ZSTRIDE + 16 * bj + r];
  }
  __syncthreads();
  if (wv == 1){                              // wave 1 stages its partial sum
    #pragma unroll
    for (int ai = 0; ai < 4; ++ai)
      #pragma unroll
      for (int bj = 0; bj < 4; ++bj)
        #pragma unroll
        for (int e = 0; e < 4; ++e)
          z0[(16 * ai + g * 4 + e) * ZSTRIDE + 16 * bj + r] = acc[ai][bj][e];
  }
  __syncthreads();
  if (wv == 0){                              // wave 0: final sum + store to P
    #pragma unroll
    for (int ai = 0; ai < 4; ++ai)
      #pragma unroll
      for (int bj = 0; bj < 4; ++bj)
        #pragma unroll
        for (int e = 0; e < 4; ++e)
          acc[ai][bj][e] += z0[(16 * ai + g * 4 + e) * ZSTRIDE + 16 * bj + r];
    // stage final into z1 (b128-aligned rows), then vector-store to P
    #pragma unroll
    for (int ai = 0; ai < 4; ++ai)
      #pragma unroll
      for (int bj = 0; bj < 4; ++bj)
        #pragma unroll
        for (int e = 0; e < 4; ++e)
          z1[(16 * ai + g * 4 + e) * ZSTRIDE + 16 * bj + r] = acc[ai][bj][e];
    float4* Pp = (float4*)(P + (size_t)blockIdx.x * 4096);
    #pragma unroll
    for (int j = 0; j < 16; ++j){
      int i4 = j * 64 + lane;                // 0..1023 float4 slots
      int row = i4 >> 4, c4 = (i4 & 15) << 2;
      Pp[i4] = *(const float4*)&z1[row * ZSTRIDE + c4];
    }
  }
}

// ---- kernel 3: reduce partials -> hist -> entropies -> output, chained ----
__global__ __launch_bounds__(256) void k_finish(const float* __restrict__ P,
                                                float* __restrict__ hist,
                                                float* __restrict__ ratio,
                                                int* __restrict__ cnt,
                                                float* __restrict__ out){
  __shared__ float4 sh4[16][17];
  __shared__ int flag;
  __shared__ float rowsum[NB], colsum[NB], wr1[4], wr2[4], S_sh;
  const int tid = threadIdx.x;
  const int n = blockIdx.x >> 6, c = blockIdx.x & 63;
  {
    const int fi = tid & 15, p4 = tid >> 4;           // 16 float4 x 16 groups
    const float4* P4 = (const float4*)P;
    size_t base = ((size_t)n * WPS + (size_t)p4 * 8) * 1024 + c * 16 + fi;
    float4 acc = make_float4(0.f, 0.f, 0.f, 0.f);
    #pragma unroll
    for (int w = 0; w < 8; ++w){
      float4 vv = P4[base + (size_t)w * 1024];
      acc.x += vv.x; acc.y += vv.y; acc.z += vv.z; acc.w += vv.w;
    }
    sh4[p4][fi] = acc;
    __syncthreads();
    if (tid < 16){
      float4 s = sh4[0][tid];
      #pragma unroll
      for (int p = 1; p < 16; ++p){
        float4 a = sh4[p][tid];
        s.x += a.x; s.y += a.y; s.z += a.z; s.w += a.w;
      }
      ((float4*)hist)[(size_t)n * 1024 + c * 16 + tid] = s;
    }
  }
  __threadfence();
  __syncthreads();
  if (tid == 0) flag = atomicAdd(&cnt[n], 1);
  __syncthreads();
  if (flag != 63) return;                           // not the last chunk
  __threadfence();
  // entropies for sample n (this block only)
  float* h = hist + n * 4096;
  if (tid < NB){ rowsum[tid] = 0.f; colsum[tid] = 0.f; }
  __syncthreads();
  const int rr = tid >> 2, c0 = (tid & 3) * 16;
  float hv[16];
  float rsum = 0.f;
  #pragma unroll
  for (int k = 0; k < 16; ++k){
    hv[k] = atomicAdd(&h[rr * 64 + c0 + k], 0.f);   // coherent read
    rsum += hv[k];
  }
  atomicAdd(&rowsum[rr], rsum);
  #pragma unroll
  for (int k = 0; k < 16; ++k) atomicAdd(&colsum[c0 + k], hv[k]);
  float part = rsum;
  for (int off = 32; off; off >>= 1) part += __shfl_down(part, off);
  if ((tid & 63) == 0) wr1[tid >> 6] = part;
  __syncthreads();
  if (tid == 0) S_sh = wr1[0] + wr1[1] + wr1[2] + wr1[3];
  __syncthreads();
  const float invS = 1.f / S_sh;
  float ej = 0.f;
  #pragma unroll
  for (int k = 0; k < 16; ++k){
    float p = hv[k] * invS;
    ej -= p * logf(p + 1e-12f);
  }
  for (int off = 32; off; off >>= 1) ej += __shfl_down(ej, off);
  if ((tid & 63) == 0) wr2[tid >> 6] = ej;
  float em = 0.f;
  if (tid < NB){
    float pt = rowsum[tid] * invS;
    float ps = colsum[tid] * invS;
    em = -pt * logf(pt + 1e-12f) - ps * logf(ps + 1e-12f);
    for (int off = 32; off; off >>= 1) em += __shfl_down(em, off);
  }
  __syncthreads();
  if (tid == 0){
    float EJ = wr2[0] + wr2[1] + wr2[2] + wr2[3];
    ratio[n] = em / EJ;                             // (Ht + Hs) / Hj
    __threadfence();
    int f2 = atomicAdd(&cnt[4], 1);
    if (f2 == NSAMP - 1){                           // last sample finisher
      __threadfence();
      float s = 0.f;
      #pragma unroll
      for (int m = 0; m < NSAMP; ++m) s += atomicAdd(&ratio[m], 0.f);
      out[0] = -0.25f * s;
    }
  }
}

extern "C" void kernel_launch(void* const* d_in, const int* in_sizes, int n_in,
                              void* d_out, int out_size, void* d_ws, size_t ws_size,
                              hipStream_t stream){
  const float* tgt = (const float*)d_in[0];
  const float* src = (const float*)d_in[1];
  float* out = (float*)d_out;
  char* ws = (char*)d_ws;
  // ws: [0,4K) mmp 256*float4 | [4K,+32) cnt | [4352,+16) ratio |
  //     [4608,+64K) hist | [73728, +8.4MB) P partials
  float4* mmp = (float4*)ws;
  int*   cnt  = (int*)(ws + 4096);
  float* ratio= (float*)(ws + 4352);
  float* hist = (float*)(ws + 4608);
  float* P    = (float*)(ws + 73728);
  k_minmax<<<NSAMP * 64, 256, 0, stream>>>(tgt, src, mmp, cnt);
  k_hist  <<<NSAMP * WPS, 256, 0, stream>>>(tgt, src, mmp, P);
  k_finish<<<NSAMP * 64, 256, 0, stream>>>(P, hist, ratio, cnt, out);
}